// Round 4
// baseline (218.546 us; speedup 1.0000x reference)
//
#include <hip/hip_runtime.h>

#define NLAT 255
#define NLON 256
#define NPIX 49152
#define MMAX 129
#define MCS  258      // 2*MMAX
#define NTBL 65       // distinct ring geometries
#define TROWS 264     // Ttab2 padded mcs rows

typedef unsigned short ushort_t;
typedef __attribute__((ext_vector_type(8)))  short  bf16x8;
typedef __attribute__((ext_vector_type(4)))  short  short4v;
typedef __attribute__((ext_vector_type(16))) float  f32x16;
typedef __attribute__((ext_vector_type(4)))  float  float4v;
typedef __attribute__((ext_vector_type(4), aligned(4))) float float4u;

__device__ __forceinline__ ushort_t f2bf(float f) {
    union { float f; unsigned u; } v; v.f = f;
    unsigned r = v.u + 0x7FFFu + ((v.u >> 16) & 1u);   // RTNE
    return (ushort_t)(r >> 16);
}
__device__ __forceinline__ float bf2f(ushort_t h) {
    union { unsigned u; float f; } v; v.u = ((unsigned)h) << 16;
    return v.f;
}

// ---------------- kernel 0: trig table --------------------------------
// Ttab2[tbl][p>>6][mcs][p&63] bf16, mask baked in (zero for p >= nph).
__global__ __launch_bounds__(256) void trigK(const float* __restrict__ phase,
                                             const float* __restrict__ mask,
                                             ushort_t* __restrict__ Ttab2) {
    const int tt  = blockIdx.x;          // 0..64
    const int mcs = blockIdx.y;          // 0..257
    const int p   = threadIdx.x;         // 0..255
    const int r   = (tt < 63) ? tt : (tt == 63 ? 63 : 64);
    float ph = phase[r * NLON + p];
    float mk = mask[r * NLON + p];
    float fm = (float)(mcs >> 1);
    float s, c;
    __sincosf(ph * fm, &s, &c);
    float val = (mcs & 1) ? (-s * mk) : (c * mk);
    Ttab2[(((size_t)tt * 4 + (p >> 6)) * TROWS + mcs) * 64 + (p & 63)] = f2bf(val);
}

// ---------------- kernel 1: stage A (ring DFT via MFMA) ----------------
// One block per ring: 512 thr (8 waves: 4 bc-strips x 2 mcs-strips),
// all 258 mcs in registers (acc[5][2]). x read exactly once.
__global__ __launch_bounds__(512, 2) void stageA(const float* __restrict__ x,
                                                 const int* __restrict__ ring_index,
                                                 const ushort_t* __restrict__ Ttab2,
                                                 ushort_t* __restrict__ f1) {
    __shared__ __align__(16) ushort_t Rs[256 * 72];   // 36864 B
    __shared__ __align__(16) ushort_t Ts[TROWS * 72]; // 38016 B

    const int r  = blockIdx.x;           // ring
    const int i1 = r + 1;
    const int nph = (i1 < 64) ? 4 * i1 : (i1 <= 192 ? 256 : 4 * (256 - i1));
    const int tbl = (i1 < 64) ? r : (i1 <= 192 ? (63 + (((i1 - 63) & 1) ^ 1)) : 254 - r);
    const int base = ring_index[r * NLON];

    const int t    = threadIdx.x;
    const int lane = t & 63;
    const int wid  = t >> 6;
    const int wrow = wid >> 1, wcol = wid & 1;
    const int lg   = lane >> 5;
    const int lc   = lane & 31;

    // per-tile Ts row (clamped for the ragged 5th tile; bad cols discarded)
    int trow[5];
#pragma unroll
    for (int tau = 0; tau < 5; ++tau) {
        int rr = tau * 64 + wcol * 32 + lc;
        trow[tau] = rr > (TROWS - 1) ? (TROWS - 1) : rr;
    }

    f32x16 acc[5][2];
#pragma unroll
    for (int tau = 0; tau < 5; ++tau)
#pragma unroll
        for (int i = 0; i < 2; ++i)
#pragma unroll
            for (int q = 0; q < 16; ++q) acc[tau][i][q] = 0.f;

    for (int pc = 0; pc < nph; pc += 64) {
        // ---- Rs fill: x fp32 -> bf16, once per element ----
        {
            const int p0 = (t & 15) * 4;
            const bool ok = (pc + p0) < nph;
#pragma unroll
            for (int pass = 0; pass < 8; ++pass) {
                int bc = (t >> 4) + pass * 32;
                float4v v = {0.f, 0.f, 0.f, 0.f};
                if (ok) v = *(const float4v*)(x + (size_t)bc * NPIX + base + pc + p0);
                short4v h;
                h[0] = (short)f2bf(v[0]); h[1] = (short)f2bf(v[1]);
                h[2] = (short)f2bf(v[2]); h[3] = (short)f2bf(v[3]);
                *(short4v*)(Rs + bc * 72 + p0) = h;
            }
        }
        // ---- Ts fill: contiguous slab copy ----
        {
            const ushort_t* slab = Ttab2 + ((size_t)tbl * 4 + (pc >> 6)) * (TROWS * 64);
#pragma unroll
            for (int pass = 0; pass < 5; ++pass) {
                int id = t + pass * 512;
                if (id < (TROWS * 64 / 8)) {
                    bf16x8 v = *(const bf16x8*)(slab + id * 8);
                    *(bf16x8*)(Ts + (id >> 3) * 72 + (id & 7) * 8) = v;
                }
            }
        }
        __syncthreads();
        // ---- MFMA: a-loads amortized over 5 mcs tiles ----
#pragma unroll
        for (int ks = 0; ks < 4; ++ks) {
            bf16x8 a0 = *(const bf16x8*)(Rs + (wrow * 64 + lc) * 72 + ks * 16 + lg * 8);
            bf16x8 a1 = *(const bf16x8*)(Rs + (wrow * 64 + 32 + lc) * 72 + ks * 16 + lg * 8);
#pragma unroll
            for (int tau = 0; tau < 5; ++tau) {
                bf16x8 b = *(const bf16x8*)(Ts + trow[tau] * 72 + ks * 16 + lg * 8);
                acc[tau][0] = __builtin_amdgcn_mfma_f32_32x32x16_bf16(a0, b, acc[tau][0], 0, 0, 0);
                acc[tau][1] = __builtin_amdgcn_mfma_f32_32x32x16_bf16(a1, b, acc[tau][1], 0, 0, 0);
            }
        }
        __syncthreads();
    }

    // ---- epilogue: per tile, stage acc -> LDS [mcs][bc] -> coalesced f1 ----
    ushort_t* Olds = Rs;                 // 64*264 u16 = 33792 B (fits in Rs)
#pragma unroll 1
    for (int tau = 0; tau < 5; ++tau) {
        __syncthreads();
        {
            const int mcsl = wcol * 32 + lc;
#pragma unroll
            for (int i = 0; i < 2; ++i)
#pragma unroll
                for (int q = 0; q < 16; ++q) {
                    int bc = wrow * 64 + i * 32 + 4 * lg + (q & 3) + 8 * (q >> 2);
                    Olds[mcsl * 264 + bc] = f2bf(acc[tau][i][q]);
                }
        }
        __syncthreads();
#pragma unroll
        for (int it = 0; it < 4; ++it) {
            int row = (t >> 5) + it * 16;
            int ch  = t & 31;
            int mcs = tau * 64 + row;
            if (mcs < MCS) {
                bf16x8 v = *(const bf16x8*)(Olds + row * 264 + ch * 8);
                int m = mcs >> 1, n = mcs & 1;
                *(bf16x8*)(f1 + ((size_t)m * NLAT + r) * 512 + n * 256 + ch * 8) = v;
            }
        }
    }
}

// ---------------- kernel 2: transpose f1[m][k][bc2] -> f1t[m][bc2][k256] ----
__global__ __launch_bounds__(256) void transK(const ushort_t* __restrict__ f1,
                                              ushort_t* __restrict__ f1t, int m0) {
    __shared__ __align__(16) ushort_t T[64][72];
    const int m  = m0 + blockIdx.x;
    const int k0 = blockIdx.y * 64;
    const int b0 = blockIdx.z * 64;
    const int t  = threadIdx.x;
#pragma unroll
    for (int it = 0; it < 2; ++it) {
        int id = t + it * 256;
        int kk = id >> 3, ch = id & 7;
        int k  = k0 + kk;
        bf16x8 v = {0,0,0,0,0,0,0,0};
        if (k < NLAT)
            v = *(const bf16x8*)(f1 + ((size_t)m * NLAT + k) * 512 + b0 + ch * 8);
        *(bf16x8*)(&T[kk][ch * 8]) = v;
    }
    __syncthreads();
#pragma unroll
    for (int it = 0; it < 2; ++it) {
        int id  = t + it * 256;
        int bb  = id & 63, ch8 = id >> 6;
        bf16x8 v;
#pragma unroll
        for (int j = 0; j < 8; ++j) v[j] = T[ch8 * 8 + j][bb];
        *(bf16x8*)(f1t + ((size_t)m * 512 + b0 + bb) * 256 + k0 + ch8 * 8) = v;
    }
}

// ---------------- kernel 3: stage B (Legendre via MFMA) ----------------
__global__ __launch_bounds__(256) void stageB(const ushort_t* __restrict__ f1t,
                                              const float* __restrict__ pct,
                                              const float* __restrict__ w,
                                              ushort_t* __restrict__ otmp,
                                              int mbase) {
    __shared__ __align__(16) ushort_t SB[17408];     // Ws dbuf | Es alias
    ushort_t* WsB = SB;
    ushort_t* EsB = SB;

    int m, sub;
    if (mbase == 0) { m = blockIdx.x >> 3; sub = blockIdx.x & 7; }
    else {
        int id = blockIdx.x;
        m = mbase + ((id >> 6) << 3) + (id & 7);
        sub = (id >> 3) & 7;
        if (m >= MMAX) return;
    }
    const int b2t = (sub & 3) * 128;
    const int lt  = (sub >> 2) * 128;

    const int t    = threadIdx.x;
    const int lane = t & 63;
    const int wid  = t >> 6;
    const int wrow = wid >> 1, wcol = wid & 1;
    const int lg   = lane >> 5, lc = lane & 31;

    const int flr   = t >> 1;
    const int fhalf = t & 1;
    const int gl    = lt + flr;

    f32x16 acc[2][2];
#pragma unroll
    for (int i = 0; i < 2; ++i)
#pragma unroll
        for (int j = 0; j < 2; ++j)
#pragma unroll
            for (int q = 0; q < 16; ++q) acc[i][j][q] = 0.f;

    const ushort_t* arow0 = f1t + ((size_t)m * 512 + b2t + wrow * 64 + lc) * 256;
    const ushort_t* arow1 = arow0 + 32 * 256;

    auto fill = [&](ushort_t* buf, int kc) {
        const int kb = kc + fhalf * 16;
        float vals[16];
        if (gl < NLAT) {
            const float* src = pct + ((size_t)m * NLAT + gl) * NLAT + kb;
#pragma unroll
            for (int c = 0; c < 4; ++c) {
                int k4 = kb + c * 4;
                if (k4 + 4 <= NLAT) {
                    float4u pv = *(const float4u*)(src + c * 4);
                    float4v wv = *(const float4v*)(w + k4);
#pragma unroll
                    for (int j = 0; j < 4; ++j) vals[c * 4 + j] = pv[j] * wv[j];
                } else {
#pragma unroll
                    for (int j = 0; j < 4; ++j) {
                        int k = k4 + j;
                        vals[c * 4 + j] = (k < NLAT) ? src[c * 4 + j] * w[k] : 0.f;
                    }
                }
            }
        } else {
#pragma unroll
            for (int c = 0; c < 16; ++c) vals[c] = 0.f;
        }
        ushort_t* dst = buf + flr * 40 + fhalf * 16;
#pragma unroll
        for (int c = 0; c < 4; ++c) {
            short4v h;
            h[0] = (short)f2bf(vals[c * 4 + 0]);
            h[1] = (short)f2bf(vals[c * 4 + 1]);
            h[2] = (short)f2bf(vals[c * 4 + 2]);
            h[3] = (short)f2bf(vals[c * 4 + 3]);
            *(short4v*)(dst + c * 4) = h;
        }
    };

    fill(WsB, 0);
    __syncthreads();
    int buf = 0;
    for (int kc = 0; kc < 256; kc += 32, buf ^= 1) {
        if (kc + 32 < 256) fill(WsB + (buf ^ 1) * 5120, kc + 32);
        const ushort_t* W = WsB + buf * 5120;
#pragma unroll
        for (int ks = 0; ks < 2; ++ks) {
            const int kb = kc + ks * 16 + lg * 8;
            bf16x8 b0 = *(const bf16x8*)(W + (wcol * 64 + lc) * 40 + ks * 16 + lg * 8);
            bf16x8 b1 = *(const bf16x8*)(W + (wcol * 64 + 32 + lc) * 40 + ks * 16 + lg * 8);
            bf16x8 a0 = *(const bf16x8*)(arow0 + kb);
            bf16x8 a1 = *(const bf16x8*)(arow1 + kb);
            acc[0][0] = __builtin_amdgcn_mfma_f32_32x32x16_bf16(a0, b0, acc[0][0], 0, 0, 0);
            acc[0][1] = __builtin_amdgcn_mfma_f32_32x32x16_bf16(a0, b1, acc[0][1], 0, 0, 0);
            acc[1][0] = __builtin_amdgcn_mfma_f32_32x32x16_bf16(a1, b0, acc[1][0], 0, 0, 0);
            acc[1][1] = __builtin_amdgcn_mfma_f32_32x32x16_bf16(a1, b1, acc[1][1], 0, 0, 0);
        }
        __syncthreads();
    }

#pragma unroll
    for (int i = 0; i < 2; ++i)
#pragma unroll
        for (int jj = 0; jj < 2; ++jj) {
            int ll = wcol * 64 + jj * 32 + lc;
#pragma unroll
            for (int q = 0; q < 16; ++q) {
                int bl = wrow * 64 + i * 32 + 4 * lg + (q & 3) + 8 * (q >> 2);
                EsB[bl * 136 + ll] = f2bf(acc[i][jj][q]);
            }
        }
    __syncthreads();
#pragma unroll
    for (int it = 0; it < 8; ++it) {
        int id2 = t + it * 256;
        int row = id2 >> 4, ch = id2 & 15;
        bf16x8 v = *(const bf16x8*)(EsB + row * 136 + ch * 8);
        *(bf16x8*)(otmp + (((size_t)m * 512 + b2t + row) << 8) + lt + ch * 8) = v;
    }
}

// ---------------- kernel 4: permute to out[bc][l][m][n] ----------------
__global__ __launch_bounds__(256) void permuteK(const ushort_t* __restrict__ otmp,
                                                float* __restrict__ out) {
    __shared__ ushort_t L[MCS * 66];
    const int bc = blockIdx.x;
    const int l0 = blockIdx.y * 64;
    const int t  = threadIdx.x;
    const int ll = t & 63;
    const int l  = l0 + ll;
#pragma unroll 4
    for (int it = 0; it < 65; ++it) {
        int mn = (t >> 6) + it * 4;
        if (mn < MCS) {
            int mm = mn >> 1, n = mn & 1;
            ushort_t v = 0;
            if (l < NLAT)
                v = otmp[(((size_t)mm * 512 + n * 256 + bc) << 8) + l];
            L[mn * 66 + ll] = v;
        }
    }
    __syncthreads();
    for (int ll2 = 0; ll2 < 64; ++ll2) {
        int lo = l0 + ll2;
        if (lo >= NLAT) break;
        size_t rowb = ((size_t)bc * NLAT + lo) * MCS;
        out[rowb + t] = bf2f(L[t * 66 + ll2]);
        if (t < 2)
            out[rowb + 256 + t] = bf2f(L[(256 + t) * 66 + ll2]);
    }
}

extern "C" void kernel_launch(void* const* d_in, const int* in_sizes, int n_in,
                              void* d_out, int out_size, void* d_ws, size_t ws_size,
                              hipStream_t stream) {
    const float* x          = (const float*)d_in[0];
    const float* pct        = (const float*)d_in[1];
    const float* w          = (const float*)d_in[2];
    const int*   ring_index = (const int*)d_in[3];
    const float* ring_mask  = (const float*)d_in[4];
    const float* phase      = (const float*)d_in[5];
    float* out = (float*)d_out;

    // ws choreography (total exactly 67,368,960 B):
    //   f1    @ 0          [129][255][512] u16 = 33,684,480 B
    //   Ttab2 @ 33,684,480 [65][4][264][64] u16 = 8,785,920 B (dead after stageA)
    //   f1t   @ 33,552,384 [129][512][256] u16 = 33,816,576 B (overlaps f1 m=128 tail
    //                                             + Ttab2; 2-phase transK makes it safe)
    //   otmp  @ 0          [129][512][256] u16 (overlaps f1t m<2 head; 2-phase stageB)
    char* wsb = (char*)d_ws;
    ushort_t* f1    = (ushort_t*)wsb;
    ushort_t* Ttab2 = (ushort_t*)(wsb + 33684480);
    ushort_t* f1t   = (ushort_t*)(wsb + 33552384);
    ushort_t* otmp  = (ushort_t*)wsb;

    trigK   <<<dim3(NTBL, MCS), 256, 0, stream>>>(phase, ring_mask, Ttab2);
    stageA  <<<dim3(NLAT),      512, 0, stream>>>(x, ring_index, Ttab2, f1);
    transK  <<<dim3(1, 4, 8),   256, 0, stream>>>(f1, f1t, 128);  // m=128 first
    transK  <<<dim3(128, 4, 8), 256, 0, stream>>>(f1, f1t, 0);    // m=0..127
    stageB  <<<dim3(16),        256, 0, stream>>>(f1t, pct, w, otmp, 0);  // m=0,1 first
    stageB  <<<dim3(1024),      256, 0, stream>>>(f1t, pct, w, otmp, 2);  // m=2..128
    permuteK<<<dim3(256, 4),    256, 0, stream>>>(otmp, out);
}

// Round 5
// 135.746 us; speedup vs baseline: 1.6100x; 1.6100x over previous
//
#include <hip/hip_runtime.h>

#define NLAT 255
#define NLON 256
#define NPIX 49152
#define MMAX 129
#define MCS  258      // 2*MMAX
#define NTBL 65       // distinct ring geometries
#define TROWS 264     // Ttab2 padded mcs rows

typedef unsigned short ushort_t;
typedef __attribute__((ext_vector_type(8)))  short  bf16x8;
typedef __attribute__((ext_vector_type(4)))  short  short4v;
typedef __attribute__((ext_vector_type(16))) float  f32x16;
typedef __attribute__((ext_vector_type(4)))  float  float4v;
typedef __attribute__((ext_vector_type(4), aligned(4))) float float4u;

__device__ __forceinline__ ushort_t f2bf(float f) {
    union { float f; unsigned u; } v; v.f = f;
    unsigned r = v.u + 0x7FFFu + ((v.u >> 16) & 1u);   // RTNE
    return (ushort_t)(r >> 16);
}
__device__ __forceinline__ float bf2f(ushort_t h) {
    union { unsigned u; float f; } v; v.u = ((unsigned)h) << 16;
    return v.f;
}

// ---------------- kernel 0: trig table --------------------------------
// Ttab2[tbl][p>>6][mcs][p&63] bf16, mask baked in (zero for p >= nph).
// Rows 258..263 are zero-filled padding (read by the ragged 5th tile).
__global__ __launch_bounds__(256) void trigK(const float* __restrict__ phase,
                                             const float* __restrict__ mask,
                                             ushort_t* __restrict__ Ttab2) {
    const int tt  = blockIdx.x;          // 0..64
    const int mcs = blockIdx.y;          // 0..263
    const int p   = threadIdx.x;         // 0..255
    const int r   = (tt < 63) ? tt : (tt == 63 ? 63 : 64);
    float val = 0.f;
    if (mcs < MCS) {
        float ph = phase[r * NLON + p];
        float mk = mask[r * NLON + p];
        float fm = (float)(mcs >> 1);
        float s, c;
        __sincosf(ph * fm, &s, &c);
        val = (mcs & 1) ? (-s * mk) : (c * mk);
    }
    Ttab2[(((size_t)tt * 4 + (p >> 6)) * TROWS + mcs) * 64 + (p & 63)] = f2bf(val);
}

// ---------------- kernel 1: stage A (ring DFT via MFMA) ----------------
// One block per ring: 512 thr (8 waves: 4 bc-strips x 2 mcs-strips),
// all 258 mcs in registers (acc[5][2], statically indexed everywhere).
__global__ __launch_bounds__(512, 2) void stageA(const float* __restrict__ x,
                                                 const int* __restrict__ ring_index,
                                                 const ushort_t* __restrict__ Ttab2,
                                                 ushort_t* __restrict__ f1) {
    __shared__ __align__(16) ushort_t Rs[256 * 72];   // 36864 B
    __shared__ __align__(16) ushort_t Ts[TROWS * 72]; // 38016 B

    const int r  = blockIdx.x;           // ring
    const int i1 = r + 1;
    const int nph = (i1 < 64) ? 4 * i1 : (i1 <= 192 ? 256 : 4 * (256 - i1));
    const int tbl = (i1 < 64) ? r : (i1 <= 192 ? (63 + (((i1 - 63) & 1) ^ 1)) : 254 - r);
    const int base = ring_index[r * NLON];

    const int t    = threadIdx.x;
    const int lane = t & 63;
    const int wid  = t >> 6;
    const int wrow = wid >> 1, wcol = wid & 1;
    const int lg   = lane >> 5;
    const int lc   = lane & 31;

    f32x16 acc[5][2];
#pragma unroll
    for (int tau = 0; tau < 5; ++tau)
#pragma unroll
        for (int i = 0; i < 2; ++i)
#pragma unroll
            for (int q = 0; q < 16; ++q) acc[tau][i][q] = 0.f;

    for (int pc = 0; pc < nph; pc += 64) {
        // ---- Rs fill: x fp32 -> bf16, once per element ----
        {
            const int p0 = (t & 15) * 4;
            const bool ok = (pc + p0) < nph;
#pragma unroll
            for (int pass = 0; pass < 8; ++pass) {
                int bc = (t >> 4) + pass * 32;
                float4v v = {0.f, 0.f, 0.f, 0.f};
                if (ok) v = *(const float4v*)(x + (size_t)bc * NPIX + base + pc + p0);
                short4v h;
                h[0] = (short)f2bf(v[0]); h[1] = (short)f2bf(v[1]);
                h[2] = (short)f2bf(v[2]); h[3] = (short)f2bf(v[3]);
                *(short4v*)(Rs + bc * 72 + p0) = h;
            }
        }
        // ---- Ts fill: contiguous slab copy ----
        {
            const ushort_t* slab = Ttab2 + ((size_t)tbl * 4 + (pc >> 6)) * (TROWS * 64);
#pragma unroll
            for (int pass = 0; pass < 5; ++pass) {
                int id = t + pass * 512;
                if (id < (TROWS * 64 / 8)) {
                    bf16x8 v = *(const bf16x8*)(slab + id * 8);
                    *(bf16x8*)(Ts + (id >> 3) * 72 + (id & 7) * 8) = v;
                }
            }
        }
        __syncthreads();
        // ---- MFMA: a-loads amortized over 5 mcs tiles ----
#pragma unroll
        for (int ks = 0; ks < 4; ++ks) {
            bf16x8 a0 = *(const bf16x8*)(Rs + (wrow * 64 + lc) * 72 + ks * 16 + lg * 8);
            bf16x8 a1 = *(const bf16x8*)(Rs + (wrow * 64 + 32 + lc) * 72 + ks * 16 + lg * 8);
#pragma unroll
            for (int tau = 0; tau < 5; ++tau) {
                int rr = tau * 64 + wcol * 32 + lc;
                int trow = rr > (TROWS - 1) ? (TROWS - 1) : rr;
                bf16x8 b = *(const bf16x8*)(Ts + trow * 72 + ks * 16 + lg * 8);
                acc[tau][0] = __builtin_amdgcn_mfma_f32_32x32x16_bf16(a0, b, acc[tau][0], 0, 0, 0);
                acc[tau][1] = __builtin_amdgcn_mfma_f32_32x32x16_bf16(a1, b, acc[tau][1], 0, 0, 0);
            }
        }
        __syncthreads();
    }

    // ---- epilogue: per tile, stage acc -> LDS [mcs][bc] -> coalesced f1 ----
    // FULLY UNROLLED over tau: all acc indices compile-time constant (rule #20).
    ushort_t* Olds = Rs;                 // 64*264 u16 = 33792 B (fits in Rs)
#pragma unroll
    for (int tau = 0; tau < 5; ++tau) {
        __syncthreads();
        {
            const int mcsl = wcol * 32 + lc;
#pragma unroll
            for (int i = 0; i < 2; ++i)
#pragma unroll
                for (int q = 0; q < 16; ++q) {
                    int bc = wrow * 64 + i * 32 + 4 * lg + (q & 3) + 8 * (q >> 2);
                    Olds[mcsl * 264 + bc] = f2bf(acc[tau][i][q]);
                }
        }
        __syncthreads();
#pragma unroll
        for (int it = 0; it < 4; ++it) {
            int row = (t >> 5) + it * 16;
            int ch  = t & 31;
            int mcs = tau * 64 + row;
            if (mcs < MCS) {
                bf16x8 v = *(const bf16x8*)(Olds + row * 264 + ch * 8);
                int m = mcs >> 1, n = mcs & 1;
                *(bf16x8*)(f1 + ((size_t)m * NLAT + r) * 512 + n * 256 + ch * 8) = v;
            }
        }
    }
}

// ---------------- kernel 2: transpose f1[m][k][bc2] -> f1t[m][bc2][k256] ----
__global__ __launch_bounds__(256) void transK(const ushort_t* __restrict__ f1,
                                              ushort_t* __restrict__ f1t, int m0) {
    __shared__ __align__(16) ushort_t T[64][72];
    const int m  = m0 + blockIdx.x;
    const int k0 = blockIdx.y * 64;
    const int b0 = blockIdx.z * 64;
    const int t  = threadIdx.x;
#pragma unroll
    for (int it = 0; it < 2; ++it) {
        int id = t + it * 256;
        int kk = id >> 3, ch = id & 7;
        int k  = k0 + kk;
        bf16x8 v = {0,0,0,0,0,0,0,0};
        if (k < NLAT)
            v = *(const bf16x8*)(f1 + ((size_t)m * NLAT + k) * 512 + b0 + ch * 8);
        *(bf16x8*)(&T[kk][ch * 8]) = v;
    }
    __syncthreads();
#pragma unroll
    for (int it = 0; it < 2; ++it) {
        int id  = t + it * 256;
        int bb  = id & 63, ch8 = id >> 6;
        bf16x8 v;
#pragma unroll
        for (int j = 0; j < 8; ++j) v[j] = T[ch8 * 8 + j][bb];
        *(bf16x8*)(f1t + ((size_t)m * 512 + b0 + bb) * 256 + k0 + ch8 * 8) = v;
    }
}

// ---------------- kernel 3: stage B (Legendre via MFMA) ----------------
__global__ __launch_bounds__(256) void stageB(const ushort_t* __restrict__ f1t,
                                              const float* __restrict__ pct,
                                              const float* __restrict__ w,
                                              ushort_t* __restrict__ otmp,
                                              int mbase) {
    __shared__ __align__(16) ushort_t SB[17408];     // Ws dbuf | Es alias
    ushort_t* WsB = SB;
    ushort_t* EsB = SB;

    int m, sub;
    if (mbase == 0) { m = blockIdx.x >> 3; sub = blockIdx.x & 7; }
    else {
        int id = blockIdx.x;
        m = mbase + ((id >> 6) << 3) + (id & 7);
        sub = (id >> 3) & 7;
        if (m >= MMAX) return;
    }
    const int b2t = (sub & 3) * 128;
    const int lt  = (sub >> 2) * 128;

    const int t    = threadIdx.x;
    const int lane = t & 63;
    const int wid  = t >> 6;
    const int wrow = wid >> 1, wcol = wid & 1;
    const int lg   = lane >> 5, lc = lane & 31;

    const int flr   = t >> 1;
    const int fhalf = t & 1;
    const int gl    = lt + flr;

    f32x16 acc[2][2];
#pragma unroll
    for (int i = 0; i < 2; ++i)
#pragma unroll
        for (int j = 0; j < 2; ++j)
#pragma unroll
            for (int q = 0; q < 16; ++q) acc[i][j][q] = 0.f;

    const ushort_t* arow0 = f1t + ((size_t)m * 512 + b2t + wrow * 64 + lc) * 256;
    const ushort_t* arow1 = arow0 + 32 * 256;

    auto fill = [&](ushort_t* buf, int kc) {
        const int kb = kc + fhalf * 16;
        float vals[16];
        if (gl < NLAT) {
            const float* src = pct + ((size_t)m * NLAT + gl) * NLAT + kb;
#pragma unroll
            for (int c = 0; c < 4; ++c) {
                int k4 = kb + c * 4;
                if (k4 + 4 <= NLAT) {
                    float4u pv = *(const float4u*)(src + c * 4);
                    float4v wv = *(const float4v*)(w + k4);
#pragma unroll
                    for (int j = 0; j < 4; ++j) vals[c * 4 + j] = pv[j] * wv[j];
                } else {
#pragma unroll
                    for (int j = 0; j < 4; ++j) {
                        int k = k4 + j;
                        vals[c * 4 + j] = (k < NLAT) ? src[c * 4 + j] * w[k] : 0.f;
                    }
                }
            }
        } else {
#pragma unroll
            for (int c = 0; c < 16; ++c) vals[c] = 0.f;
        }
        ushort_t* dst = buf + flr * 40 + fhalf * 16;
#pragma unroll
        for (int c = 0; c < 4; ++c) {
            short4v h;
            h[0] = (short)f2bf(vals[c * 4 + 0]);
            h[1] = (short)f2bf(vals[c * 4 + 1]);
            h[2] = (short)f2bf(vals[c * 4 + 2]);
            h[3] = (short)f2bf(vals[c * 4 + 3]);
            *(short4v*)(dst + c * 4) = h;
        }
    };

    fill(WsB, 0);
    __syncthreads();
    int buf = 0;
    for (int kc = 0; kc < 256; kc += 32, buf ^= 1) {
        if (kc + 32 < 256) fill(WsB + (buf ^ 1) * 5120, kc + 32);
        const ushort_t* W = WsB + buf * 5120;
#pragma unroll
        for (int ks = 0; ks < 2; ++ks) {
            const int kb = kc + ks * 16 + lg * 8;
            bf16x8 b0 = *(const bf16x8*)(W + (wcol * 64 + lc) * 40 + ks * 16 + lg * 8);
            bf16x8 b1 = *(const bf16x8*)(W + (wcol * 64 + 32 + lc) * 40 + ks * 16 + lg * 8);
            bf16x8 a0 = *(const bf16x8*)(arow0 + kb);
            bf16x8 a1 = *(const bf16x8*)(arow1 + kb);
            acc[0][0] = __builtin_amdgcn_mfma_f32_32x32x16_bf16(a0, b0, acc[0][0], 0, 0, 0);
            acc[0][1] = __builtin_amdgcn_mfma_f32_32x32x16_bf16(a0, b1, acc[0][1], 0, 0, 0);
            acc[1][0] = __builtin_amdgcn_mfma_f32_32x32x16_bf16(a1, b0, acc[1][0], 0, 0, 0);
            acc[1][1] = __builtin_amdgcn_mfma_f32_32x32x16_bf16(a1, b1, acc[1][1], 0, 0, 0);
        }
        __syncthreads();
    }

#pragma unroll
    for (int i = 0; i < 2; ++i)
#pragma unroll
        for (int jj = 0; jj < 2; ++jj) {
            int ll = wcol * 64 + jj * 32 + lc;
#pragma unroll
            for (int q = 0; q < 16; ++q) {
                int bl = wrow * 64 + i * 32 + 4 * lg + (q & 3) + 8 * (q >> 2);
                EsB[bl * 136 + ll] = f2bf(acc[i][jj][q]);
            }
        }
    __syncthreads();
#pragma unroll
    for (int it = 0; it < 8; ++it) {
        int id2 = t + it * 256;
        int row = id2 >> 4, ch = id2 & 15;
        bf16x8 v = *(const bf16x8*)(EsB + row * 136 + ch * 8);
        *(bf16x8*)(otmp + (((size_t)m * 512 + b2t + row) << 8) + lt + ch * 8) = v;
    }
}

// ---------------- kernel 4: permute to out[bc][l][m][n] ----------------
__global__ __launch_bounds__(256) void permuteK(const ushort_t* __restrict__ otmp,
                                                float* __restrict__ out) {
    __shared__ ushort_t L[MCS * 66];
    const int bc = blockIdx.x;
    const int l0 = blockIdx.y * 64;
    const int t  = threadIdx.x;
    const int ll = t & 63;
    const int l  = l0 + ll;
#pragma unroll 4
    for (int it = 0; it < 65; ++it) {
        int mn = (t >> 6) + it * 4;
        if (mn < MCS) {
            int mm = mn >> 1, n = mn & 1;
            ushort_t v = 0;
            if (l < NLAT)
                v = otmp[(((size_t)mm * 512 + n * 256 + bc) << 8) + l];
            L[mn * 66 + ll] = v;
        }
    }
    __syncthreads();
    for (int ll2 = 0; ll2 < 64; ++ll2) {
        int lo = l0 + ll2;
        if (lo >= NLAT) break;
        size_t rowb = ((size_t)bc * NLAT + lo) * MCS;
        out[rowb + t] = bf2f(L[t * 66 + ll2]);
        if (t < 2)
            out[rowb + 256 + t] = bf2f(L[(256 + t) * 66 + ll2]);
    }
}

extern "C" void kernel_launch(void* const* d_in, const int* in_sizes, int n_in,
                              void* d_out, int out_size, void* d_ws, size_t ws_size,
                              hipStream_t stream) {
    const float* x          = (const float*)d_in[0];
    const float* pct        = (const float*)d_in[1];
    const float* w          = (const float*)d_in[2];
    const int*   ring_index = (const int*)d_in[3];
    const float* ring_mask  = (const float*)d_in[4];
    const float* phase      = (const float*)d_in[5];
    float* out = (float*)d_out;

    // ws choreography (total exactly 67,368,960 B):
    //   f1    @ 0          [129][255][512] u16 = 33,684,480 B
    //   Ttab2 @ 33,684,480 [65][4][264][64] u16 = 8,785,920 B (dead after stageA)
    //   f1t   @ 33,552,384 [129][512][256] u16 = 33,816,576 B (overlaps f1 m=128 tail
    //                                             + Ttab2; 2-phase transK makes it safe)
    //   otmp  @ 0          [129][512][256] u16 (overlaps f1t m<2 head; 2-phase stageB)
    char* wsb = (char*)d_ws;
    ushort_t* f1    = (ushort_t*)wsb;
    ushort_t* Ttab2 = (ushort_t*)(wsb + 33684480);
    ushort_t* f1t   = (ushort_t*)(wsb + 33552384);
    ushort_t* otmp  = (ushort_t*)wsb;

    trigK   <<<dim3(NTBL, TROWS), 256, 0, stream>>>(phase, ring_mask, Ttab2);
    stageA  <<<dim3(NLAT),      512, 0, stream>>>(x, ring_index, Ttab2, f1);
    transK  <<<dim3(1, 4, 8),   256, 0, stream>>>(f1, f1t, 128);  // m=128 first
    transK  <<<dim3(128, 4, 8), 256, 0, stream>>>(f1, f1t, 0);    // m=0..127
    stageB  <<<dim3(16),        256, 0, stream>>>(f1t, pct, w, otmp, 0);  // m=0,1 first
    stageB  <<<dim3(1024),      256, 0, stream>>>(f1t, pct, w, otmp, 2);  // m=2..128
    permuteK<<<dim3(256, 4),    256, 0, stream>>>(otmp, out);
}